// Round 7
// baseline (15822.473 us; speedup 1.0000x reference)
//
#include <hip/hip_runtime.h>

#define VOCAB 32000
#define EMBD  512
#define HIDD  1024
#define SLEN  512
#define NBAT  4
#define GATE4 4096   // 4*HIDD
#define ABLK  128    // layer-0 blocks, 8 units each
#define BBLK  256    // layer-1 blocks, 4 units each

typedef unsigned long long u64;

// ---------------- embedding gather ----------------
__global__ void embed_k(const int* __restrict__ ids, const float* __restrict__ emb,
                        float* __restrict__ X0) {
  const int n  = blockIdx.x;             // 0..2047 (= b*SLEN + s)
  const int id = ids[n];
  ((float4*)X0)[(size_t)n*(EMBD/4) + threadIdx.x] =
      ((const float4*)emb)[(size_t)id*(EMBD/4) + threadIdx.x];
}

// ---------------- 32x32 tiled transpose: [1024][4096] -> [4096][1024] -------
__global__ __launch_bounds__(256) void transpose_k(const float* __restrict__ src,
                                                   float* __restrict__ dst) {
  __shared__ float t[32][33];
  const int bx = blockIdx.x * 32;   // col base (0..4095)
  const int by = blockIdx.y * 32;   // row base (0..1023)
  const int r0 = threadIdx.x >> 5;  // 0..7
  const int c  = threadIdx.x & 31;
  #pragma unroll
  for (int i = 0; i < 4; i++) {
    const int r = r0 + i*8;
    t[r][c] = src[(size_t)(by + r)*GATE4 + bx + c];
  }
  __syncthreads();
  #pragma unroll
  for (int i = 0; i < 4; i++) {
    const int rw = r0 + i*8;
    dst[(size_t)(bx + rw)*HIDD + by + c] = t[c][rw];
  }
}

// ---------------- f32 tiled GEMM: C = A@B + bias ----------------
__global__ __launch_bounds__(256) void gemm_nn_bias(
    const float* __restrict__ A, const float* __restrict__ B,
    const float* __restrict__ bias, float* __restrict__ C,
    int M, int N, int K) {
  __shared__ float As[16][64];
  __shared__ float Bs[16][64];
  const int tid = threadIdx.x;
  const int bm = blockIdx.y * 64;
  const int bn = blockIdx.x * 64;
  const int tx = tid & 15, ty = tid >> 4;
  const int mA = tid >> 2, kqA = (tid & 3) * 4;
  const int kB = tid >> 4, nB = (tid & 15) * 4;
  float acc[4][4] = {{0.f}};
  for (int k0 = 0; k0 < K; k0 += 16) {
    float4 a4 = *(const float4*)(A + (size_t)(bm + mA)*K + k0 + kqA);
    As[kqA+0][mA] = a4.x; As[kqA+1][mA] = a4.y;
    As[kqA+2][mA] = a4.z; As[kqA+3][mA] = a4.w;
    *(float4*)&Bs[kB][nB] = *(const float4*)(B + (size_t)(k0 + kB)*N + bn + nB);
    __syncthreads();
    #pragma unroll
    for (int k = 0; k < 16; k++) {
      float4 av = *(float4*)&As[k][ty*4];
      float4 bv = *(float4*)&Bs[k][tx*4];
      float ar[4] = {av.x, av.y, av.z, av.w};
      float br[4] = {bv.x, bv.y, bv.z, bv.w};
      #pragma unroll
      for (int i = 0; i < 4; i++)
        #pragma unroll
        for (int j = 0; j < 4; j++)
          acc[i][j] += ar[i] * br[j];
    }
    __syncthreads();
  }
  float4 bi = *(const float4*)(bias + bn + tx*4);
  #pragma unroll
  for (int i = 0; i < 4; i++) {
    float4 o;
    o.x = acc[i][0] + bi.x; o.y = acc[i][1] + bi.y;
    o.z = acc[i][2] + bi.z; o.w = acc[i][3] + bi.w;
    *(float4*)(C + (size_t)(bm + ty*4 + i)*N + bn + tx*4) = o;
  }
}

// ---------------- logits GEMM: C = A @ Bt^T, with pad-mask ----------------
__global__ __launch_bounds__(256) void gemm_nt_logits(
    const float* __restrict__ A,   // P [2048, 512] (in d_ws — must NOT alias C)
    const float* __restrict__ Bt,  // emb [32000, 512]
    const int* __restrict__ ids,   // [2048]
    float* __restrict__ C) {       // [2048, 32000]
  const int K = EMBD, N = VOCAB;
  __shared__ float As[16][64];
  __shared__ float Bs[16][64];
  const int tid = threadIdx.x;
  const int bm = blockIdx.y * 64;
  const int bn = blockIdx.x * 64;
  const int tx = tid & 15, ty = tid >> 4;
  const int rA = tid >> 2, kq = (tid & 3) * 4;
  float acc[4][4] = {{0.f}};
  for (int k0 = 0; k0 < K; k0 += 16) {
    float4 a4 = *(const float4*)(A  + (size_t)(bm + rA)*K + k0 + kq);
    float4 b4 = *(const float4*)(Bt + (size_t)(bn + rA)*K + k0 + kq);
    As[kq+0][rA] = a4.x; As[kq+1][rA] = a4.y; As[kq+2][rA] = a4.z; As[kq+3][rA] = a4.w;
    Bs[kq+0][rA] = b4.x; Bs[kq+1][rA] = b4.y; Bs[kq+2][rA] = b4.z; Bs[kq+3][rA] = b4.w;
    __syncthreads();
    #pragma unroll
    for (int k = 0; k < 16; k++) {
      float4 av = *(float4*)&As[k][ty*4];
      float4 bv = *(float4*)&Bs[k][tx*4];
      float ar[4] = {av.x, av.y, av.z, av.w};
      float br[4] = {bv.x, bv.y, bv.z, bv.w};
      #pragma unroll
      for (int i = 0; i < 4; i++)
        #pragma unroll
        for (int j = 0; j < 4; j++)
          acc[i][j] += ar[i] * br[j];
    }
    __syncthreads();
  }
  #pragma unroll
  for (int i = 0; i < 4; i++) {
    const int row = bm + ty*4 + i;
    const bool mk = ids[row] != 0;
    float4 o;
    if (mk) { o.x = acc[i][0]; o.y = acc[i][1]; o.z = acc[i][2]; o.w = acc[i][3]; }
    else    { o.x = (bn + tx*4 == 0) ? 1.f : 0.f; o.y = 0.f; o.z = 0.f; o.w = 0.f; }
    *(float4*)(C + (size_t)row*N + bn + tx*4) = o;
  }
}

// ---------------- fused 2-layer pipelined LSTM recurrence -------------------
// 384 uniform blocks (4 waves, <=256 VGPR -> 2 blocks/CU capacity 512 >= 384:
// co-residency guaranteed in any dispatch order).
// A-blocks (0..127): layer-0, 8 units each; publish h0(t)->Hx0, flagA=t+1.
// B-blocks (128..383): layer-1, 4 units each; z1 = Wk1T*h0(t) + Wr1T*h1(t-1)
//   + b1 fused in one accumulator pass; h1(t) -> H1 global + Hx1, flagB=t+1.
// Waits: B(t): {flagA>=t+1, flagB>=t}. A(t): {flagA>=t, flagB>=t-1}
// (2-slot parity overwrite safety both directions; graph acyclic).
// All exchange via relaxed agent-scope atomics; readiness = plain flag store
// after wave-scoped s_waitcnt vmcnt(0). No fences anywhere.
__device__ __forceinline__ int rev5(int l) {
  return ((l & 1) << 4) | ((l & 2) << 2) | (l & 4) | ((l & 8) >> 2) | ((l & 16) >> 4);
}

#define HALVE(MASK, SH, HSZ)                          \
    { const int bit_ = (lane >> SH) & 1;              \
      _Pragma("unroll")                               \
      for (int j = 0; j < HSZ; j++) {                 \
        float snd = bit_ ? a[j] : a[j + HSZ];         \
        float kep = bit_ ? a[j + HSZ] : a[j];         \
        a[j] = kep + __shfl_xor(snd, MASK);           \
      } }

__global__ __launch_bounds__(256, 2) void lstm_fused(
    const float* __restrict__ Z0,    // [B*S, 4096] x@Wk0 + b0
    const float* __restrict__ Wr0T,  // [4096, 1024]
    const float* __restrict__ Wk1T,  // [4096, 1024]
    const float* __restrict__ Wr1T,  // [4096, 1024]
    const float* __restrict__ bias1, // [4096]
    const int* __restrict__ ids,     // [B*S]
    float* __restrict__ H1,          // [B*S, 1024] layer-1 h sequence
    float* __restrict__ Hx0,         // [2][4096] h0 exchange
    float* __restrict__ Hx1,         // [2][4096] h1 exchange
    unsigned* __restrict__ flgA,     // [128*16] (zeroed)
    unsigned* __restrict__ flgB) {   // [256*16] (zeroed)
  __shared__ float h0_s[NBAT * HIDD];
  __shared__ float h1_s[NBAT * HIDD];
  __shared__ float z_s[4][64];
  __shared__ float zc[128];
  const int tid  = threadIdx.x;
  const int lane = tid & 63;
  const int w    = tid >> 6;
  const int ccH  = tid >> 7;
  const int part = tid & 127;

  if (blockIdx.x < ABLK) {
    // ================= role A: layer-0, 8 units =================
    const int hbase = blockIdx.x * 8;
    float4 Wf[16], Wg[16];
    #pragma unroll
    for (int cl = 0; cl < 16; cl++) {
      const int cc = ccH * 16 + cl;
      const int g  = cc >> 3, d = cc & 7;
      const size_t col = (size_t)(g * HIDD + hbase + d);
      Wf[cl] = *(const float4*)(Wr0T + col * HIDD + 4 * part);
      Wg[cl] = *(const float4*)(Wr0T + col * HIDD + 512 + 4 * part);
    }
    float c_reg = 0.f, h_reg = 0.f;
    for (int i = tid; i < NBAT * HIDD; i += 256) h0_s[i] = 0.f;
    __syncthreads();

    for (int t = 0; t < SLEN; t++) {
      float pz0 = 0.f, pz1 = 0.f, pz2 = 0.f, pz3 = 0.f;
      int pmk = 0;
      if (tid < 32) {
        const int b = tid >> 3, d = tid & 7;
        const float* zrow = Z0 + (size_t)(b*SLEN + t) * GATE4 + hbase + d;
        pz0 = zrow[0];        pz1 = zrow[HIDD];
        pz2 = zrow[2*HIDD];   pz3 = zrow[3*HIDD];
        pmk = ids[b*SLEN + t];
      }
      if (t > 0 && tid < ABLK) {
        while (__hip_atomic_load(flgA + tid * 16, __ATOMIC_RELAXED,
                                 __HIP_MEMORY_SCOPE_AGENT) < (unsigned)t)
          __builtin_amdgcn_s_sleep(1);
      }
      if (t >= 2) {  // throttle: all B gathered h0(t-2) before slot reuse
        while (__hip_atomic_load(flgB + tid * 16, __ATOMIC_RELAXED,
                                 __HIP_MEMORY_SCOPE_AGENT) < (unsigned)(t - 1))
          __builtin_amdgcn_s_sleep(1);
      }
      __syncthreads();
      if (t > 0) {
        const u64* src = (const u64*)(Hx0 + (size_t)((t - 1) & 1) * (NBAT*HIDD));
        u64 v[8];
        #pragma unroll
        for (int r = 0; r < 8; r++)
          v[r] = __hip_atomic_load(src + tid + (r << 8),
                                   __ATOMIC_RELAXED, __HIP_MEMORY_SCOPE_AGENT);
        #pragma unroll
        for (int r = 0; r < 8; r++) ((u64*)h0_s)[tid + (r << 8)] = v[r];
        __syncthreads();
      }
      float4 ha[NBAT], hb[NBAT];
      #pragma unroll
      for (int b = 0; b < NBAT; b++) {
        ha[b] = ((const float4*)h0_s)[b*256 + part];
        hb[b] = ((const float4*)h0_s)[b*256 + 128 + part];
      }
      float a[64];
      #pragma unroll
      for (int cl = 0; cl < 16; cl++) {
        #pragma unroll
        for (int b = 0; b < NBAT; b++) {
          a[cl*4 + b] = Wf[cl].x*ha[b].x + Wf[cl].y*ha[b].y
                      + Wf[cl].z*ha[b].z + Wf[cl].w*ha[b].w
                      + Wg[cl].x*hb[b].x + Wg[cl].y*hb[b].y
                      + Wg[cl].z*hb[b].z + Wg[cl].w*hb[b].w;
        }
      }
      #pragma unroll
      for (int i = 0; i < 64; i++) a[i] += __shfl_xor(a[i], 32);
      HALVE(1, 0, 32) HALVE(2, 1, 16) HALVE(4, 2, 8) HALVE(8, 3, 4) HALVE(16, 4, 2)
      if (lane < 32) {
        z_s[w][rev5(lane)*2 + 0] = a[0];
        z_s[w][rev5(lane)*2 + 1] = a[1];
      }
      __syncthreads();
      if (tid < 128) {
        const int cc = tid >> 2, b = tid & 3;
        const int cH = cc >> 4, i = ((cc & 15) << 2) | b;
        zc[tid] = z_s[2*cH][i] + z_s[2*cH + 1][i];
      }
      __syncthreads();
      if (tid < 32) {
        const int b = tid >> 3, d = tid & 7;
        const float zi = zc[((0*8 + d) << 2) + b] + pz0;
        const float zf = zc[((1*8 + d) << 2) + b] + pz1;
        const float zg = zc[((2*8 + d) << 2) + b] + pz2;
        const float zo = zc[((3*8 + d) << 2) + b] + pz3;
        const float ig = 1.f / (1.f + expf(-zi));
        const float fg = 1.f / (1.f + expf(-zf));
        const float gg = tanhf(zg);
        const float og = 1.f / (1.f + expf(-zo));
        const float cn = fg * c_reg + ig * gg;
        const float hn = og * tanhf(cn);
        const bool mk = pmk != 0;
        const float ho = mk ? hn : h_reg;
        c_reg = mk ? cn : c_reg;
        h_reg = ho;
        __hip_atomic_store(Hx0 + (size_t)(t & 1) * (NBAT*HIDD)
                              + b * HIDD + hbase + d, ho,
                           __ATOMIC_RELAXED, __HIP_MEMORY_SCOPE_AGENT);
      }
      if (w == 0) {
        asm volatile("s_waitcnt vmcnt(0)" ::: "memory");
        if (tid == 0)
          __hip_atomic_store(flgA + blockIdx.x * 16, (unsigned)(t + 1),
                             __ATOMIC_RELAXED, __HIP_MEMORY_SCOPE_AGENT);
      }
    }
  } else {
    // ================= role B: layer-1, 4 units =================
    const int bid = blockIdx.x - ABLK;     // 0..255
    const int ub  = bid * 4;
    float4 Kf[8], Kg[8], Rf[8], Rg[8];
    #pragma unroll
    for (int cl = 0; cl < 8; cl++) {
      const int cc = ccH * 8 + cl;
      const int g  = cc >> 2, u = cc & 3;
      const size_t col = (size_t)(g * HIDD + ub + u);
      Kf[cl] = *(const float4*)(Wk1T + col * HIDD + 4 * part);
      Kg[cl] = *(const float4*)(Wk1T + col * HIDD + 512 + 4 * part);
      Rf[cl] = *(const float4*)(Wr1T + col * HIDD + 4 * part);
      Rg[cl] = *(const float4*)(Wr1T + col * HIDD + 512 + 4 * part);
    }
    float pbi = 0.f, pbf = 0.f, pbg = 0.f, pbo = 0.f;
    if (tid < 16) {
      const int u = tid & 3;
      pbi = bias1[0*HIDD + ub + u];
      pbf = bias1[1*HIDD + ub + u];
      pbg = bias1[2*HIDD + ub + u];
      pbo = bias1[3*HIDD + ub + u];
    }
    float c_reg = 0.f, h_reg = 0.f;
    for (int i = tid; i < NBAT * HIDD; i += 256) h1_s[i] = 0.f;
    __syncthreads();

    for (int t = 0; t < SLEN; t++) {
      int pmk = 0;
      if (tid < 16) pmk = ids[(tid >> 2) * SLEN + t];
      if (tid < ABLK) {   // h0(t) ready?
        while (__hip_atomic_load(flgA + tid * 16, __ATOMIC_RELAXED,
                                 __HIP_MEMORY_SCOPE_AGENT) < (unsigned)(t + 1))
          __builtin_amdgcn_s_sleep(1);
      }
      if (t > 0) {        // h1(t-1) ready (also slot safety)?
        while (__hip_atomic_load(flgB + tid * 16, __ATOMIC_RELAXED,
                                 __HIP_MEMORY_SCOPE_AGENT) < (unsigned)t)
          __builtin_amdgcn_s_sleep(1);
      }
      __syncthreads();
      {
        const u64* s0 = (const u64*)(Hx0 + (size_t)(t & 1) * (NBAT*HIDD));
        u64 v0[8];
        #pragma unroll
        for (int r = 0; r < 8; r++)
          v0[r] = __hip_atomic_load(s0 + tid + (r << 8),
                                    __ATOMIC_RELAXED, __HIP_MEMORY_SCOPE_AGENT);
        u64 v1[8];
        if (t > 0) {
          const u64* s1 = (const u64*)(Hx1 + (size_t)((t - 1) & 1) * (NBAT*HIDD));
          #pragma unroll
          for (int r = 0; r < 8; r++)
            v1[r] = __hip_atomic_load(s1 + tid + (r << 8),
                                      __ATOMIC_RELAXED, __HIP_MEMORY_SCOPE_AGENT);
        }
        #pragma unroll
        for (int r = 0; r < 8; r++) ((u64*)h0_s)[tid + (r << 8)] = v0[r];
        if (t > 0) {
          #pragma unroll
          for (int r = 0; r < 8; r++) ((u64*)h1_s)[tid + (r << 8)] = v1[r];
        }
        __syncthreads();
      }
      float4 xa[NBAT], xb[NBAT], ya[NBAT], yb[NBAT];
      #pragma unroll
      for (int b = 0; b < NBAT; b++) {
        xa[b] = ((const float4*)h0_s)[b*256 + part];
        xb[b] = ((const float4*)h0_s)[b*256 + 128 + part];
        ya[b] = ((const float4*)h1_s)[b*256 + part];
        yb[b] = ((const float4*)h1_s)[b*256 + 128 + part];
      }
      float a[32];
      #pragma unroll
      for (int cl = 0; cl < 8; cl++) {
        #pragma unroll
        for (int b = 0; b < NBAT; b++) {
          a[cl*4 + b] = Kf[cl].x*xa[b].x + Kf[cl].y*xa[b].y
                      + Kf[cl].z*xa[b].z + Kf[cl].w*xa[b].w
                      + Kg[cl].x*xb[b].x + Kg[cl].y*xb[b].y
                      + Kg[cl].z*xb[b].z + Kg[cl].w*xb[b].w
                      + Rf[cl].x*ya[b].x + Rf[cl].y*ya[b].y
                      + Rf[cl].z*ya[b].z + Rf[cl].w*ya[b].w
                      + Rg[cl].x*yb[b].x + Rg[cl].y*yb[b].y
                      + Rg[cl].z*yb[b].z + Rg[cl].w*yb[b].w;
        }
      }
      #pragma unroll
      for (int i = 0; i < 32; i++) a[i] += __shfl_xor(a[i], 32);
      HALVE(1, 0, 16) HALVE(2, 1, 8) HALVE(4, 2, 4) HALVE(8, 3, 2) HALVE(16, 4, 1)
      if (lane < 32) z_s[w][rev5(lane)] = a[0];
      __syncthreads();
      if (tid < 64) {
        const int h_ = tid >> 5, i5 = tid & 31;
        zc[tid] = z_s[2*h_][i5] + z_s[2*h_ + 1][i5];
      }
      __syncthreads();
      if (tid < 16) {
        const int b = tid >> 2, u = tid & 3;
        const float zi = zc[      u      * 4 + b] + pbi;
        const float zf = zc[     (4 + u) * 4 + b] + pbf;
        const float zg = zc[32 +  u      * 4 + b] + pbg;
        const float zo = zc[32 + (4 + u) * 4 + b] + pbo;
        const float ig = 1.f / (1.f + expf(-zi));
        const float fg = 1.f / (1.f + expf(-zf));
        const float gg = tanhf(zg);
        const float og = 1.f / (1.f + expf(-zo));
        const float cn = fg * c_reg + ig * gg;
        const float hn = og * tanhf(cn);
        const bool mk = pmk != 0;
        const float ho = mk ? hn : h_reg;
        c_reg = mk ? cn : c_reg;
        h_reg = ho;
        H1[(size_t)(b*SLEN + t) * HIDD + ub + u] = ho;
        __hip_atomic_store(Hx1 + (size_t)(t & 1) * (NBAT*HIDD)
                              + b * HIDD + ub + u, ho,
                           __ATOMIC_RELAXED, __HIP_MEMORY_SCOPE_AGENT);
      }
      if (w == 0) {
        asm volatile("s_waitcnt vmcnt(0)" ::: "memory");
        if (tid == 0)
          __hip_atomic_store(flgB + bid * 16, (unsigned)(t + 1),
                             __ATOMIC_RELAXED, __HIP_MEMORY_SCOPE_AGENT);
      }
    }
  }
}
#undef HALVE

extern "C" void kernel_launch(void* const* d_in, const int* in_sizes, int n_in,
                              void* d_out, int out_size, void* d_ws, size_t ws_size,
                              hipStream_t stream) {
  const int*   ids = (const int*)  d_in[0];
  const float* emb = (const float*)d_in[1];
  const float* Wk0 = (const float*)d_in[2];
  const float* Wr0 = (const float*)d_in[3];
  const float* b0  = (const float*)d_in[4];
  const float* Wk1 = (const float*)d_in[5];
  const float* Wr1 = (const float*)d_in[6];
  const float* b1  = (const float*)d_in[7];
  const float* Wp  = (const float*)d_in[8];
  const float* bp  = (const float*)d_in[9];
  float* out = (float*)d_out;

  // DEAD-before-logits intermediates live in the head of d_out; cross-kernel
  // live data (flags, Hx, P) lives in d_ws (~4.2 MB).
  float* X0    = out;                  // [2048,  512]  1,048,576 f
  float* Z     = out + 1048576;        // [2048, 4096]  8,388,608 f (L0 only)
  float* H1    = out + 9437184;        // [2048, 1024]  2,097,152 f
  float* Wr0T  = out + 11534336;       // [4096, 1024]  4,194,304 f
  float* Wr1T  = out + 15728640;       // [4096, 1024]  4,194,304 f
  float* Wk1T  = out + 19922944;       // [4096, 1024]  4,194,304 f
  unsigned* flgA = (unsigned*)d_ws;              // [128*16] u32 = 8 KB
  unsigned* flgB = (unsigned*)d_ws + 2048;       // [256*16] u32 = 16 KB
  float* Hx0 = ((float*)d_ws) + 6144;  // [2][4096] f32 = 32 KB
  float* Hx1 = ((float*)d_ws) + 14336; // [2][4096] f32 = 32 KB
  float* P   = ((float*)d_ws) + 22528; // [2048, 512] 1,048,576 f = 4 MB

  hipMemsetAsync(d_ws, 0, 24576, stream);  // zero both flag arrays
  embed_k<<<2048, 128, 0, stream>>>(ids, emb, X0);
  transpose_k<<<dim3(128, 32), 256, 0, stream>>>(Wr0, Wr0T);
  transpose_k<<<dim3(128, 32), 256, 0, stream>>>(Wr1, Wr1T);
  transpose_k<<<dim3(128, 32), 256, 0, stream>>>(Wk1, Wk1T);
  gemm_nn_bias<<<dim3(64, 32), 256, 0, stream>>>(X0, Wk0, b0, Z, 2048, 4096, 512);
  lstm_fused<<<ABLK + BBLK, 256, 0, stream>>>(Z, Wr0T, Wk1T, Wr1T, b1, ids,
                                              H1, Hx0, Hx1, flgA, flgB);
  gemm_nn_bias<<<dim3(8, 32), 256, 0, stream>>>(H1, Wp, bp, P, 2048, 512, 1024);
  gemm_nt_logits<<<dim3(500, 32), 256, 0, stream>>>(P, emb, ids, out);
}

// Round 8
// 7492.686 us; speedup vs baseline: 2.1117x; 2.1117x over previous
//
#include <hip/hip_runtime.h>

#define VOCAB 32000
#define EMBD  512
#define HIDD  1024
#define SLEN  512
#define NBAT  4
#define GATE4 4096   // 4*HIDD
#define ABLK  128    // layer-0 blocks, 8 units each
#define BBLK  256    // layer-1 blocks, 4 units each

typedef unsigned long long u64;

// ---------------- embedding gather ----------------
__global__ void embed_k(const int* __restrict__ ids, const float* __restrict__ emb,
                        float* __restrict__ X0) {
  const int n  = blockIdx.x;             // 0..2047 (= b*SLEN + s)
  const int id = ids[n];
  ((float4*)X0)[(size_t)n*(EMBD/4) + threadIdx.x] =
      ((const float4*)emb)[(size_t)id*(EMBD/4) + threadIdx.x];
}

// ---------------- 32x32 tiled transpose: [1024][4096] -> [4096][1024] -------
__global__ __launch_bounds__(256) void transpose_k(const float* __restrict__ src,
                                                   float* __restrict__ dst) {
  __shared__ float t[32][33];
  const int bx = blockIdx.x * 32;   // col base (0..4095)
  const int by = blockIdx.y * 32;   // row base (0..1023)
  const int r0 = threadIdx.x >> 5;  // 0..7
  const int c  = threadIdx.x & 31;
  #pragma unroll
  for (int i = 0; i < 4; i++) {
    const int r = r0 + i*8;
    t[r][c] = src[(size_t)(by + r)*GATE4 + bx + c];
  }
  __syncthreads();
  #pragma unroll
  for (int i = 0; i < 4; i++) {
    const int rw = r0 + i*8;
    dst[(size_t)(bx + rw)*HIDD + by + c] = t[c][rw];
  }
}

// ---------------- f32 tiled GEMM: C = A@B + bias ----------------
__global__ __launch_bounds__(256) void gemm_nn_bias(
    const float* __restrict__ A, const float* __restrict__ B,
    const float* __restrict__ bias, float* __restrict__ C,
    int M, int N, int K) {
  __shared__ float As[16][64];
  __shared__ float Bs[16][64];
  const int tid = threadIdx.x;
  const int bm = blockIdx.y * 64;
  const int bn = blockIdx.x * 64;
  const int tx = tid & 15, ty = tid >> 4;
  const int mA = tid >> 2, kqA = (tid & 3) * 4;
  const int kB = tid >> 4, nB = (tid & 15) * 4;
  float acc[4][4] = {{0.f}};
  for (int k0 = 0; k0 < K; k0 += 16) {
    float4 a4 = *(const float4*)(A + (size_t)(bm + mA)*K + k0 + kqA);
    As[kqA+0][mA] = a4.x; As[kqA+1][mA] = a4.y;
    As[kqA+2][mA] = a4.z; As[kqA+3][mA] = a4.w;
    *(float4*)&Bs[kB][nB] = *(const float4*)(B + (size_t)(k0 + kB)*N + bn + nB);
    __syncthreads();
    #pragma unroll
    for (int k = 0; k < 16; k++) {
      float4 av = *(float4*)&As[k][ty*4];
      float4 bv = *(float4*)&Bs[k][tx*4];
      float ar[4] = {av.x, av.y, av.z, av.w};
      float br[4] = {bv.x, bv.y, bv.z, bv.w};
      #pragma unroll
      for (int i = 0; i < 4; i++)
        #pragma unroll
        for (int j = 0; j < 4; j++)
          acc[i][j] += ar[i] * br[j];
    }
    __syncthreads();
  }
  float4 bi = *(const float4*)(bias + bn + tx*4);
  #pragma unroll
  for (int i = 0; i < 4; i++) {
    float4 o;
    o.x = acc[i][0] + bi.x; o.y = acc[i][1] + bi.y;
    o.z = acc[i][2] + bi.z; o.w = acc[i][3] + bi.w;
    *(float4*)(C + (size_t)(bm + ty*4 + i)*N + bn + tx*4) = o;
  }
}

// ---------------- logits GEMM: C = A @ Bt^T, with pad-mask ----------------
__global__ __launch_bounds__(256) void gemm_nt_logits(
    const float* __restrict__ A,   // P [2048, 512] (in d_ws — must NOT alias C)
    const float* __restrict__ Bt,  // emb [32000, 512]
    const int* __restrict__ ids,   // [2048]
    float* __restrict__ C) {       // [2048, 32000]
  const int K = EMBD, N = VOCAB;
  __shared__ float As[16][64];
  __shared__ float Bs[16][64];
  const int tid = threadIdx.x;
  const int bm = blockIdx.y * 64;
  const int bn = blockIdx.x * 64;
  const int tx = tid & 15, ty = tid >> 4;
  const int rA = tid >> 2, kq = (tid & 3) * 4;
  float acc[4][4] = {{0.f}};
  for (int k0 = 0; k0 < K; k0 += 16) {
    float4 a4 = *(const float4*)(A  + (size_t)(bm + rA)*K + k0 + kq);
    float4 b4 = *(const float4*)(Bt + (size_t)(bn + rA)*K + k0 + kq);
    As[kq+0][rA] = a4.x; As[kq+1][rA] = a4.y; As[kq+2][rA] = a4.z; As[kq+3][rA] = a4.w;
    Bs[kq+0][rA] = b4.x; Bs[kq+1][rA] = b4.y; Bs[kq+2][rA] = b4.z; Bs[kq+3][rA] = b4.w;
    __syncthreads();
    #pragma unroll
    for (int k = 0; k < 16; k++) {
      float4 av = *(float4*)&As[k][ty*4];
      float4 bv = *(float4*)&Bs[k][tx*4];
      float ar[4] = {av.x, av.y, av.z, av.w};
      float br[4] = {bv.x, bv.y, bv.z, bv.w};
      #pragma unroll
      for (int i = 0; i < 4; i++)
        #pragma unroll
        for (int j = 0; j < 4; j++)
          acc[i][j] += ar[i] * br[j];
    }
    __syncthreads();
  }
  #pragma unroll
  for (int i = 0; i < 4; i++) {
    const int row = bm + ty*4 + i;
    const bool mk = ids[row] != 0;
    float4 o;
    if (mk) { o.x = acc[i][0]; o.y = acc[i][1]; o.z = acc[i][2]; o.w = acc[i][3]; }
    else    { o.x = (bn + tx*4 == 0) ? 1.f : 0.f; o.y = 0.f; o.z = 0.f; o.w = 0.f; }
    *(float4*)(C + (size_t)row*N + bn + tx*4) = o;
  }
}

// ---------------- fused 2-layer pipelined LSTM recurrence -------------------
// 384 blocks, 4 waves, launch_bounds(256,1) -> full 256-VGPR budget (round-7's
// (256,2) capped VGPR at 128 and spilled weights -> 8.4 GB scratch traffic).
// A-blocks (0..127): layer-0, 8 units; STREAM h0(t) into H0full[t] (no slot
//   reuse -> A never waits on B -> dependency graph A->A, A->B, B->B is
//   acyclic even without full co-residency; no deadlock in any schedule).
// B-blocks (128..383): layer-1, 4 units; z1 = Wk1T*h0(t) + Wr1T*h1(t-1) + b1
//   computed in two register passes (lower live-range pressure).
// Exchange: relaxed agent-scope atomics; readiness flags stored by wave 0
// after s_waitcnt vmcnt(0). Hx1 2-slot parity safe (B(t+1) requires all B
// finished t, i.e. already gathered h1(t-1), before slot (t-1)&1 is rewritten).
__device__ __forceinline__ int rev5(int l) {
  return ((l & 1) << 4) | ((l & 2) << 2) | (l & 4) | ((l & 8) >> 2) | ((l & 16) >> 4);
}

#define HALVE(MASK, SH, HSZ)                          \
    { const int bit_ = (lane >> SH) & 1;              \
      _Pragma("unroll")                               \
      for (int j = 0; j < HSZ; j++) {                 \
        float snd = bit_ ? a[j] : a[j + HSZ];         \
        float kep = bit_ ? a[j + HSZ] : a[j];         \
        a[j] = kep + __shfl_xor(snd, MASK);           \
      } }

__global__ __launch_bounds__(256, 1) void lstm_fused(
    const float* __restrict__ Z0,     // [B*S, 4096] x@Wk0 + b0
    const float* __restrict__ Wr0T,   // [4096, 1024]
    const float* __restrict__ Wk1T,   // [4096, 1024]
    const float* __restrict__ Wr1T,   // [4096, 1024]
    const float* __restrict__ bias1,  // [4096]
    const int* __restrict__ ids,      // [B*S]
    float* __restrict__ H1,           // [B*S, 1024] layer-1 h sequence
    float* __restrict__ H0full,       // [SLEN][4096] streamed h0
    float* __restrict__ Hx1,          // [2][4096] h1 exchange
    unsigned* __restrict__ flgA,      // [128*16] (zeroed)
    unsigned* __restrict__ flgB) {    // [256*16] (zeroed)
  __shared__ float h0_s[NBAT * HIDD];
  __shared__ float h1_s[NBAT * HIDD];
  __shared__ float z_s[4][64];
  __shared__ float zc[128];
  const int tid  = threadIdx.x;
  const int lane = tid & 63;
  const int w    = tid >> 6;
  const int ccH  = tid >> 7;
  const int part = tid & 127;

  if (blockIdx.x < ABLK) {
    // ================= role A: layer-0, 8 units =================
    const int hbase = blockIdx.x * 8;
    float4 Wf[16], Wg[16];
    #pragma unroll
    for (int cl = 0; cl < 16; cl++) {
      const int cc = ccH * 16 + cl;
      const int g  = cc >> 3, d = cc & 7;
      const size_t col = (size_t)(g * HIDD + hbase + d);
      Wf[cl] = *(const float4*)(Wr0T + col * HIDD + 4 * part);
      Wg[cl] = *(const float4*)(Wr0T + col * HIDD + 512 + 4 * part);
    }
    float c_reg = 0.f, h_reg = 0.f;
    for (int i = tid; i < NBAT * HIDD; i += 256) h0_s[i] = 0.f;
    __syncthreads();

    for (int t = 0; t < SLEN; t++) {
      float pz0 = 0.f, pz1 = 0.f, pz2 = 0.f, pz3 = 0.f;
      int pmk = 0;
      if (tid < 32) {
        const int b = tid >> 3, d = tid & 7;
        const float* zrow = Z0 + (size_t)(b*SLEN + t) * GATE4 + hbase + d;
        pz0 = zrow[0];        pz1 = zrow[HIDD];
        pz2 = zrow[2*HIDD];   pz3 = zrow[3*HIDD];
        pmk = ids[b*SLEN + t];
      }
      if (t > 0) {
        if (tid < ABLK) {
          while (__hip_atomic_load(flgA + tid * 16, __ATOMIC_RELAXED,
                                   __HIP_MEMORY_SCOPE_AGENT) < (unsigned)t)
            __builtin_amdgcn_s_sleep(1);
        }
        __syncthreads();
        const u64* src = (const u64*)(H0full + (size_t)(t - 1) * (NBAT*HIDD));
        u64 v[8];
        #pragma unroll
        for (int r = 0; r < 8; r++)
          v[r] = __hip_atomic_load(src + tid + (r << 8),
                                   __ATOMIC_RELAXED, __HIP_MEMORY_SCOPE_AGENT);
        #pragma unroll
        for (int r = 0; r < 8; r++) ((u64*)h0_s)[tid + (r << 8)] = v[r];
        __syncthreads();
      }
      float4 ha[NBAT], hb[NBAT];
      #pragma unroll
      for (int b = 0; b < NBAT; b++) {
        ha[b] = ((const float4*)h0_s)[b*256 + part];
        hb[b] = ((const float4*)h0_s)[b*256 + 128 + part];
      }
      float a[64];
      #pragma unroll
      for (int cl = 0; cl < 16; cl++) {
        #pragma unroll
        for (int b = 0; b < NBAT; b++) {
          a[cl*4 + b] = Wf[cl].x*ha[b].x + Wf[cl].y*ha[b].y
                      + Wf[cl].z*ha[b].z + Wf[cl].w*ha[b].w
                      + Wg[cl].x*hb[b].x + Wg[cl].y*hb[b].y
                      + Wg[cl].z*hb[b].z + Wg[cl].w*hb[b].w;
        }
      }
      #pragma unroll
      for (int i = 0; i < 64; i++) a[i] += __shfl_xor(a[i], 32);
      HALVE(1, 0, 32) HALVE(2, 1, 16) HALVE(4, 2, 8) HALVE(8, 3, 4) HALVE(16, 4, 2)
      if (lane < 32) {
        z_s[w][rev5(lane)*2 + 0] = a[0];
        z_s[w][rev5(lane)*2 + 1] = a[1];
      }
      __syncthreads();
      if (tid < 128) {
        const int cc = tid >> 2, b = tid & 3;
        const int cH = cc >> 4, i = ((cc & 15) << 2) | b;
        zc[tid] = z_s[2*cH][i] + z_s[2*cH + 1][i];
      }
      __syncthreads();
      if (tid < 32) {
        const int b = tid >> 3, d = tid & 7;
        const float zi = zc[((0*8 + d) << 2) + b] + pz0;
        const float zf = zc[((1*8 + d) << 2) + b] + pz1;
        const float zg = zc[((2*8 + d) << 2) + b] + pz2;
        const float zo = zc[((3*8 + d) << 2) + b] + pz3;
        const float ig = 1.f / (1.f + expf(-zi));
        const float fg = 1.f / (1.f + expf(-zf));
        const float gg = tanhf(zg);
        const float og = 1.f / (1.f + expf(-zo));
        const float cn = fg * c_reg + ig * gg;
        const float hn = og * tanhf(cn);
        const bool mk = pmk != 0;
        const float ho = mk ? hn : h_reg;
        c_reg = mk ? cn : c_reg;
        h_reg = ho;
        __hip_atomic_store(H0full + (size_t)t * (NBAT*HIDD)
                              + b * HIDD + hbase + d, ho,
                           __ATOMIC_RELAXED, __HIP_MEMORY_SCOPE_AGENT);
      }
      if (w == 0) {
        asm volatile("s_waitcnt vmcnt(0)" ::: "memory");
        if (tid == 0)
          __hip_atomic_store(flgA + blockIdx.x * 16, (unsigned)(t + 1),
                             __ATOMIC_RELAXED, __HIP_MEMORY_SCOPE_AGENT);
      }
    }
  } else {
    // ================= role B: layer-1, 4 units =================
    const int bid = blockIdx.x - ABLK;     // 0..255
    const int ub  = bid * 4;
    float4 Kf[8], Kg[8], Rf[8], Rg[8];
    #pragma unroll
    for (int cl = 0; cl < 8; cl++) {
      const int cc = ccH * 8 + cl;
      const int g  = cc >> 2, u = cc & 3;
      const size_t col = (size_t)(g * HIDD + ub + u);
      Kf[cl] = *(const float4*)(Wk1T + col * HIDD + 4 * part);
      Kg[cl] = *(const float4*)(Wk1T + col * HIDD + 512 + 4 * part);
      Rf[cl] = *(const float4*)(Wr1T + col * HIDD + 4 * part);
      Rg[cl] = *(const float4*)(Wr1T + col * HIDD + 512 + 4 * part);
    }
    float pbi = 0.f, pbf = 0.f, pbg = 0.f, pbo = 0.f;
    if (tid < 16) {
      const int u = tid & 3;
      pbi = bias1[0*HIDD + ub + u];
      pbf = bias1[1*HIDD + ub + u];
      pbg = bias1[2*HIDD + ub + u];
      pbo = bias1[3*HIDD + ub + u];
    }
    float c_reg = 0.f, h_reg = 0.f;
    for (int i = tid; i < NBAT * HIDD; i += 256) h1_s[i] = 0.f;
    __syncthreads();

    for (int t = 0; t < SLEN; t++) {
      int pmk = 0;
      if (tid < 16) pmk = ids[(tid >> 2) * SLEN + t];
      if (tid < ABLK) {   // h0(t) ready?
        while (__hip_atomic_load(flgA + tid * 16, __ATOMIC_RELAXED,
                                 __HIP_MEMORY_SCOPE_AGENT) < (unsigned)(t + 1))
          __builtin_amdgcn_s_sleep(1);
      }
      if (t > 0) {        // h1(t-1) ready (also Hx1 slot safety)?
        while (__hip_atomic_load(flgB + tid * 16, __ATOMIC_RELAXED,
                                 __HIP_MEMORY_SCOPE_AGENT) < (unsigned)t)
          __builtin_amdgcn_s_sleep(1);
      }
      __syncthreads();
      {
        const u64* s0 = (const u64*)(H0full + (size_t)t * (NBAT*HIDD));
        u64 v0[8];
        #pragma unroll
        for (int r = 0; r < 8; r++)
          v0[r] = __hip_atomic_load(s0 + tid + (r << 8),
                                    __ATOMIC_RELAXED, __HIP_MEMORY_SCOPE_AGENT);
        #pragma unroll
        for (int r = 0; r < 8; r++) ((u64*)h0_s)[tid + (r << 8)] = v0[r];
        if (t > 0) {
          const u64* s1 = (const u64*)(Hx1 + (size_t)((t - 1) & 1) * (NBAT*HIDD));
          u64 v1[8];
          #pragma unroll
          for (int r = 0; r < 8; r++)
            v1[r] = __hip_atomic_load(s1 + tid + (r << 8),
                                      __ATOMIC_RELAXED, __HIP_MEMORY_SCOPE_AGENT);
          #pragma unroll
          for (int r = 0; r < 8; r++) ((u64*)h1_s)[tid + (r << 8)] = v1[r];
        }
        __syncthreads();
      }
      float a[32];
      {  // pass 1: Wk1^T * h0(t)
        float4 xa[NBAT], xb[NBAT];
        #pragma unroll
        for (int b = 0; b < NBAT; b++) {
          xa[b] = ((const float4*)h0_s)[b*256 + part];
          xb[b] = ((const float4*)h0_s)[b*256 + 128 + part];
        }
        #pragma unroll
        for (int cl = 0; cl < 8; cl++) {
          #pragma unroll
          for (int b = 0; b < NBAT; b++) {
            a[cl*4 + b] = Kf[cl].x*xa[b].x + Kf[cl].y*xa[b].y
                        + Kf[cl].z*xa[b].z + Kf[cl].w*xa[b].w
                        + Kg[cl].x*xb[b].x + Kg[cl].y*xb[b].y
                        + Kg[cl].z*xb[b].z + Kg[cl].w*xb[b].w;
          }
        }
      }
      {  // pass 2: += Wr1^T * h1(t-1)
        float4 ya[NBAT], yb[NBAT];
        #pragma unroll
        for (int b = 0; b < NBAT; b++) {
          ya[b] = ((const float4*)h1_s)[b*256 + part];
          yb[b] = ((const float4*)h1_s)[b*256 + 128 + part];
        }
        #pragma unroll
        for (int cl = 0; cl < 8; cl++) {
          #pragma unroll
          for (int b = 0; b < NBAT; b++) {
            a[cl*4 + b] += Rf[cl].x*ya[b].x + Rf[cl].y*ya[b].y
                         + Rf[cl].z*ya[b].z + Rf[cl].w*ya[b].w
                         + Rg[cl].x*yb[b].x + Rg[cl].y*yb[b].y
                         + Rg[cl].z*yb[b].z + Rg[cl].w*yb[b].w;
          }
        }
      }
      #pragma unroll
      for (int i = 0; i < 32; i++) a[i] += __shfl_xor(a[i], 32);
      HALVE(1, 0, 16) HALVE(2, 1, 8) HALVE(4, 2, 4) HALVE(8, 3, 2) HALVE(16, 4, 1)
      if (lane < 32) z_s[w][rev5(lane)] = a[0];
      __syncthreads();
      if (tid < 64) {
        const int h_ = tid >> 5, i5 = tid & 31;
        zc[tid] = z_s[2*h_][i5] + z_s[2*h_ + 1][i5];
      }
      __syncthreads();
      if (tid < 16) {
        const int b = tid >> 2, u = tid & 3;
        const float zi = zc[      u      * 4 + b] + pbi;
        const float zf = zc[     (4 + u) * 4 + b] + pbf;
        const float zg = zc[32 +  u      * 4 + b] + pbg;
        const float zo = zc[32 + (4 + u) * 4 + b] + pbo;
        const float ig = 1.f / (1.f + expf(-zi));
        const float fg = 1.f / (1.f + expf(-zf));
        const float gg = tanhf(zg);
        const float og = 1.f / (1.f + expf(-zo));
        const float cn = fg * c_reg + ig * gg;
        const float hn = og * tanhf(cn);
        const bool mk = pmk != 0;
        const float ho = mk ? hn : h_reg;
        c_reg = mk ? cn : c_reg;
        h_reg = ho;
        H1[(size_t)(b*SLEN + t) * HIDD + ub + u] = ho;
        __hip_atomic_store(Hx1 + (size_t)(t & 1) * (NBAT*HIDD)
                              + b * HIDD + ub + u, ho,
                           __ATOMIC_RELAXED, __HIP_MEMORY_SCOPE_AGENT);
      }
      if (w == 0) {
        asm volatile("s_waitcnt vmcnt(0)" ::: "memory");
        if (tid == 0)
          __hip_atomic_store(flgB + bid * 16, (unsigned)(t + 1),
                             __ATOMIC_RELAXED, __HIP_MEMORY_SCOPE_AGENT);
      }
    }
  }
}
#undef HALVE

extern "C" void kernel_launch(void* const* d_in, const int* in_sizes, int n_in,
                              void* d_out, int out_size, void* d_ws, size_t ws_size,
                              hipStream_t stream) {
  const int*   ids = (const int*)  d_in[0];
  const float* emb = (const float*)d_in[1];
  const float* Wk0 = (const float*)d_in[2];
  const float* Wr0 = (const float*)d_in[3];
  const float* b0  = (const float*)d_in[4];
  const float* Wk1 = (const float*)d_in[5];
  const float* Wr1 = (const float*)d_in[6];
  const float* b1  = (const float*)d_in[7];
  const float* Wp  = (const float*)d_in[8];
  const float* bp  = (const float*)d_in[9];
  float* out = (float*)d_out;

  // DEAD-before-logits intermediates live in the head of d_out; cross-kernel
  // live data (flags, Hx1, P) lives in d_ws (~4.1 MB).
  float* X0     = out;                  // [2048,  512]  1,048,576 f
  float* Z      = out + 1048576;        // [2048, 4096]  8,388,608 f (L0 only)
  float* H1     = out + 9437184;        // [2048, 1024]  2,097,152 f
  float* Wr0T   = out + 11534336;       // [4096, 1024]  4,194,304 f
  float* Wr1T   = out + 15728640;       // [4096, 1024]  4,194,304 f
  float* Wk1T   = out + 19922944;       // [4096, 1024]  4,194,304 f
  float* H0full = out + 24117248;       // [512, 4096]   2,097,152 f
  unsigned* flgA = (unsigned*)d_ws;              // [128*16] u32 = 8 KB
  unsigned* flgB = (unsigned*)d_ws + 2048;       // [256*16] u32 = 16 KB
  float* Hx1 = ((float*)d_ws) + 6144;   // [2][4096] f32 = 32 KB
  float* P   = ((float*)d_ws) + 14336;  // [2048, 512] 1,048,576 f = 4 MB

  hipMemsetAsync(d_ws, 0, 24576, stream);  // zero both flag arrays
  embed_k<<<2048, 128, 0, stream>>>(ids, emb, X0);
  transpose_k<<<dim3(128, 32), 256, 0, stream>>>(Wr0, Wr0T);
  transpose_k<<<dim3(128, 32), 256, 0, stream>>>(Wr1, Wr1T);
  transpose_k<<<dim3(128, 32), 256, 0, stream>>>(Wk1, Wk1T);
  gemm_nn_bias<<<dim3(64, 32), 256, 0, stream>>>(X0, Wk0, b0, Z, 2048, 4096, 512);
  lstm_fused<<<ABLK + BBLK, 256, 0, stream>>>(Z, Wr0T, Wk1T, Wr1T, b1, ids,
                                              H1, H0full, Hx1, flgA, flgB);
  gemm_nn_bias<<<dim3(8, 32), 256, 0, stream>>>(H1, Wp, bp, P, 2048, 512, 1024);
  gemm_nt_logits<<<dim3(500, 32), 256, 0, stream>>>(P, emb, ids, out);
}